// Round 2
// baseline (167.689 us; speedup 1.0000x reference)
//
#include <hip/hip_runtime.h>

#define EPS 1e-6f

// LDS row stride: 24 floats of data + 1 pad -> 25 (coprime with 32 banks:
// thread t reads base t*25, 32 lanes cover all 32 banks, wave64 = 2-way = free)
#define ROWF 25

__device__ __forceinline__ float sel8(const float v[8], int k) {
    // constant-index accesses only -> stays in registers (cndmask chain)
    float r = v[0];
#pragma unroll
    for (int i = 1; i < 8; ++i) r = (k == i) ? v[i] : r;
    return r;
}

__device__ __forceinline__ float norm2f(float dx, float dy) {
    return sqrtf(dx * dx + dy * dy);
}

__global__ __launch_bounds__(256) void gsc_loss_kernel(
    const float* __restrict__ pred, const float* __restrict__ gt,
    float* __restrict__ acc, int B)
{
    __shared__ float sP[256 * ROWF];
    __shared__ float sG[256 * ROWF];

    const int tid = threadIdx.x;
    const int blockStart = blockIdx.x * 256;

    // ---- coalesced staging: 256 rows x 6 float4 per tensor ----
    // float4 index f (block-local 0..1535): lane i reads contiguous 16B chunks.
    {
        const size_t total4 = (size_t)B * 6;
        const float4* p4 = reinterpret_cast<const float4*>(pred);
        const float4* g4 = reinterpret_cast<const float4*>(gt);
        const size_t base4 = (size_t)blockStart * 6;
#pragma unroll
        for (int i = 0; i < 6; ++i) {
            size_t f = base4 + tid + i * 256;
            if (f < total4) {
                float4 pv = p4[f];
                float4 gv = g4[f];
                int fl = tid + i * 256;          // block-local float4 index
                int r = fl / 6, c = (fl % 6) * 4;
                float* dp = &sP[r * ROWF + c];
                float* dg = &sG[r * ROWF + c];
                dp[0] = pv.x; dp[1] = pv.y; dp[2] = pv.z; dp[3] = pv.w;
                dg[0] = gv.x; dg[1] = gv.y; dg[2] = gv.z; dg[3] = gv.w;
            }
        }
    }
    __syncthreads();

    const int b = blockStart + tid;
    float L = 0.0f;
    float vflag = 0.0f;

    if (b < B) {
        const float* pb = &sP[tid * ROWF];
        const float* gb = &sG[tid * ROWF];

        // visibility mask + count
        unsigned mask = 0;
        int vcnt = 0;
#pragma unroll
        for (int k = 0; k < 8; ++k) {
            bool vis = (pb[3 * k + 2] > 0.5f) && (gb[3 * k + 2] > 0.5f);
            if (vis) { mask |= (1u << k); ++vcnt; }
        }

        // rows with <4 visible are invalid -> contribute 0; skip entirely.
        if (vcnt >= 4) {
            vflag = 1.0f;

            float px8[8], py8[8], gx8[8], gy8[8];
#pragma unroll
            for (int k = 0; k < 8; ++k) {
                px8[k] = pb[3 * k + 0]; py8[k] = pb[3 * k + 1];
                gx8[k] = gb[3 * k + 0]; gy8[k] = gb[3 * k + 1];
            }

            // first 4 visible indices (stable order = ascending bit positions)
            float px[4], py[4], gx[4], gy[4];
            unsigned m = mask;
#pragma unroll
            for (int i = 0; i < 4; ++i) {
                int k = __ffs(m) - 1;
                m &= m - 1;
                px[i] = sel8(px8, k); py[i] = sel8(py8, k);
                gx[i] = sel8(gx8, k); gy[i] = sel8(gy8, k);
            }

            // ---- L_shape: cross-ratio of diagonals ----
            float pd31x = px[2] - px[0], pd31y = py[2] - py[0];
            float pd42x = px[3] - px[1], pd42y = py[3] - py[1];
            float gd31x = gx[2] - gx[0], gd31y = gy[2] - gy[0];
            float gd42x = gx[3] - gx[1], gd42y = gy[3] - gy[1];
            float pred_cr = norm2f(pd31x, pd31y) / (norm2f(pd42x, pd42y) + EPS);
            float gt_cr   = norm2f(gd31x, gd31y) / (norm2f(gd42x, gd42y) + EPS);
            float L_shape = fabsf(pred_cr - gt_cr);

            // ---- L_edge ----
            float v12x = px[1] - px[0], v12y = py[1] - py[0];
            float v23x = px[2] - px[1], v23y = py[2] - py[1];
            float v34x = px[3] - px[2], v34y = py[3] - py[2];
            float v41x = px[0] - px[3], v41y = py[0] - py[3];
            float l12 = norm2f(v12x, v12y), l23 = norm2f(v23x, v23y);
            float l34 = norm2f(v34x, v34y), l41 = norm2f(v41x, v41y);
            float par1 = fabsf(l12 - l34) / (l12 + l34 + EPS);
            float par2 = fabsf(l23 - l41) / (l23 + l41 + EPS);
            float dot1 = fabsf((v12x * v41x + v12y * v41y) / (l12 * l41 + EPS));
            float dot2 = fabsf((v12x * v23x + v12y * v23y) / (l12 * l23 + EPS));
            float dot3 = fabsf((v23x * v34x + v23y * v34y) / (l23 * l34 + EPS));
            float dot4 = fabsf((v34x * v41x + v34y * v41y) / (l34 * l41 + EPS));
            float L_edge = 0.5f * (par1 + par2) + 0.25f * (dot1 + dot2 + dot3 + dot4);

            // ---- L_pos ----
            float dist = 0.25f * (norm2f(px[0] - gx[0], py[0] - gy[0]) +
                                  norm2f(px[1] - gx[1], py[1] - gy[1]) +
                                  norm2f(px[2] - gx[2], py[2] - gy[2]) +
                                  norm2f(px[3] - gx[3], py[3] - gy[3]));

            float p21x = px[1] - px[0], p21y = py[1] - py[0];
            float p41x = px[3] - px[0], p41y = py[3] - py[0];
            float g21x = gx[1] - gx[0], g21y = gy[1] - gy[0];
            float g41x = gx[3] - gx[0], g41y = gy[3] - gy[0];
            float pred_area = 0.5f * fabsf(p21x * pd31y - p21y * pd31x)
                            + 0.5f * fabsf(pd31x * p41y - pd31y * p41x);
            float gt_area   = 0.5f * fabsf(g21x * gd31y - g21y * gd31x)
                            + 0.5f * fabsf(gd31x * g41y - gd31y * g41x);
            float area_ratio = fabsf(pred_area - gt_area) / (gt_area + EPS);

            float mpx = 0.25f * (px[0] + px[1] + px[2] + px[3]);
            float mpy = 0.25f * (py[0] + py[1] + py[2] + py[3]);
            float mgx = 0.25f * (gx[0] + gx[1] + gx[2] + gx[3]);
            float mgy = 0.25f * (gy[0] + gy[1] + gy[2] + gy[3]);
            float rel_cons = 0.0f;
#pragma unroll
            for (int i = 0; i < 4; ++i) {
                rel_cons += norm2f((px[i] - mpx) - (gx[i] - mgx),
                                   (py[i] - mpy) - (gy[i] - mgy));
            }
            rel_cons *= 0.25f;

            float L_pos = 0.4f * dist + 0.3f * area_ratio + 0.3f * rel_cons;
            L = 0.4f * L_shape + 0.3f * L_edge + 0.3f * L_pos;
        }
    }

    // ---- reduction: wave64 shuffle -> LDS -> one atomic per block ----
#pragma unroll
    for (int off = 32; off > 0; off >>= 1) {
        L     += __shfl_down(L, off, 64);
        vflag += __shfl_down(vflag, off, 64);
    }
    __shared__ float sL[4], sV[4];
    int lane = threadIdx.x & 63;
    int wv   = threadIdx.x >> 6;
    if (lane == 0) { sL[wv] = L; sV[wv] = vflag; }
    __syncthreads();
    if (threadIdx.x == 0) {
        float tL = sL[0] + sL[1] + sL[2] + sL[3];
        float tV = sV[0] + sV[1] + sV[2] + sV[3];
        atomicAdd(&acc[0], tL);
        atomicAdd(&acc[1], tV);
    }
}

__global__ void gsc_finalize_kernel(const float* __restrict__ acc,
                                    float* __restrict__ out)
{
    float total = acc[0];
    float n     = acc[1];
    out[0] = (n > 0.0f) ? (total / n) : 0.0f;
}

extern "C" void kernel_launch(void* const* d_in, const int* in_sizes, int n_in,
                              void* d_out, int out_size, void* d_ws, size_t ws_size,
                              hipStream_t stream) {
    const float* pred = (const float*)d_in[0];
    const float* gt   = (const float*)d_in[1];
    float* out = (float*)d_out;
    float* acc = (float*)d_ws;   // [0]=sum(L), [1]=n_valid

    int B = in_sizes[0] / 24;    // 524288

    hipMemsetAsync(acc, 0, 2 * sizeof(float), stream);

    int block = 256;
    int grid = (B + block - 1) / block;
    gsc_loss_kernel<<<grid, block, 0, stream>>>(pred, gt, acc, B);
    gsc_finalize_kernel<<<1, 1, 0, stream>>>(acc, out);
}

// Round 3
// 144.130 us; speedup vs baseline: 1.1635x; 1.1635x over previous
//
#include <hip/hip_runtime.h>

#define EPS 1e-6f

__device__ __forceinline__ float sel8(const float v[8], int k) {
    // constant-index accesses only -> stays in registers (cndmask chain)
    float r = v[0];
#pragma unroll
    for (int i = 1; i < 8; ++i) r = (k == i) ? v[i] : r;
    return r;
}

__device__ __forceinline__ float norm2f(float dx, float dy) {
    return sqrtf(dx * dx + dy * dy);
}

// Stage 1: per-block partial (sum L, n_valid) -> d_ws[blockIdx]. NO atomics:
// 4096 same-line device-scope atomicAdds (~18ns each serialized) were the
// ~75us floor in R1/R2.
__global__ __launch_bounds__(256) void gsc_loss_kernel(
    const float* __restrict__ pred, const float* __restrict__ gt,
    float2* __restrict__ partials, int B)
{
    int b = blockIdx.x * blockDim.x + threadIdx.x;
    float L = 0.0f;
    float vflag = 0.0f;

    if (b < B) {
        // 24 floats (8 kpts x 3) per row per tensor; row base = 96 B (16B aligned)
        const float4* p4 = reinterpret_cast<const float4*>(pred) + (size_t)b * 6;
        const float4* g4 = reinterpret_cast<const float4*>(gt)   + (size_t)b * 6;
        float pb[24], gb[24];
#pragma unroll
        for (int i = 0; i < 6; ++i) {
            float4 pv = p4[i];
            float4 gv = g4[i];
            pb[4 * i + 0] = pv.x; pb[4 * i + 1] = pv.y;
            pb[4 * i + 2] = pv.z; pb[4 * i + 3] = pv.w;
            gb[4 * i + 0] = gv.x; gb[4 * i + 1] = gv.y;
            gb[4 * i + 2] = gv.z; gb[4 * i + 3] = gv.w;
        }

        // visibility mask + count
        unsigned mask = 0;
        int vcnt = 0;
#pragma unroll
        for (int k = 0; k < 8; ++k) {
            bool vis = (pb[3 * k + 2] > 0.5f) && (gb[3 * k + 2] > 0.5f);
            if (vis) { mask |= (1u << k); ++vcnt; }
        }

        // rows with <4 visible are invalid -> contribute 0; skip entirely.
        if (vcnt >= 4) {
            vflag = 1.0f;

            float px8[8], py8[8], gx8[8], gy8[8];
#pragma unroll
            for (int k = 0; k < 8; ++k) {
                px8[k] = pb[3 * k + 0]; py8[k] = pb[3 * k + 1];
                gx8[k] = gb[3 * k + 0]; gy8[k] = gb[3 * k + 1];
            }

            // first 4 visible indices (stable order = ascending bit positions)
            float px[4], py[4], gx[4], gy[4];
            unsigned m = mask;
#pragma unroll
            for (int i = 0; i < 4; ++i) {
                int k = __ffs(m) - 1;
                m &= m - 1;
                px[i] = sel8(px8, k); py[i] = sel8(py8, k);
                gx[i] = sel8(gx8, k); gy[i] = sel8(gy8, k);
            }

            // ---- L_shape: cross-ratio of diagonals ----
            float pd31x = px[2] - px[0], pd31y = py[2] - py[0];
            float pd42x = px[3] - px[1], pd42y = py[3] - py[1];
            float gd31x = gx[2] - gx[0], gd31y = gy[2] - gy[0];
            float gd42x = gx[3] - gx[1], gd42y = gy[3] - gy[1];
            float pred_cr = norm2f(pd31x, pd31y) / (norm2f(pd42x, pd42y) + EPS);
            float gt_cr   = norm2f(gd31x, gd31y) / (norm2f(gd42x, gd42y) + EPS);
            float L_shape = fabsf(pred_cr - gt_cr);

            // ---- L_edge ----
            float v12x = px[1] - px[0], v12y = py[1] - py[0];
            float v23x = px[2] - px[1], v23y = py[2] - py[1];
            float v34x = px[3] - px[2], v34y = py[3] - py[2];
            float v41x = px[0] - px[3], v41y = py[0] - py[3];
            float l12 = norm2f(v12x, v12y), l23 = norm2f(v23x, v23y);
            float l34 = norm2f(v34x, v34y), l41 = norm2f(v41x, v41y);
            float par1 = fabsf(l12 - l34) / (l12 + l34 + EPS);
            float par2 = fabsf(l23 - l41) / (l23 + l41 + EPS);
            float dot1 = fabsf((v12x * v41x + v12y * v41y) / (l12 * l41 + EPS));
            float dot2 = fabsf((v12x * v23x + v12y * v23y) / (l12 * l23 + EPS));
            float dot3 = fabsf((v23x * v34x + v23y * v34y) / (l23 * l34 + EPS));
            float dot4 = fabsf((v34x * v41x + v34y * v41y) / (l34 * l41 + EPS));
            float L_edge = 0.5f * (par1 + par2) + 0.25f * (dot1 + dot2 + dot3 + dot4);

            // ---- L_pos ----
            float dist = 0.25f * (norm2f(px[0] - gx[0], py[0] - gy[0]) +
                                  norm2f(px[1] - gx[1], py[1] - gy[1]) +
                                  norm2f(px[2] - gx[2], py[2] - gy[2]) +
                                  norm2f(px[3] - gx[3], py[3] - gy[3]));

            float p21x = px[1] - px[0], p21y = py[1] - py[0];
            float p41x = px[3] - px[0], p41y = py[3] - py[0];
            float g21x = gx[1] - gx[0], g21y = gy[1] - gy[0];
            float g41x = gx[3] - gx[0], g41y = gy[3] - gy[0];
            float pred_area = 0.5f * fabsf(p21x * pd31y - p21y * pd31x)
                            + 0.5f * fabsf(pd31x * p41y - pd31y * p41x);
            float gt_area   = 0.5f * fabsf(g21x * gd31y - g21y * gd31x)
                            + 0.5f * fabsf(gd31x * g41y - gd31y * g41x);
            float area_ratio = fabsf(pred_area - gt_area) / (gt_area + EPS);

            float mpx = 0.25f * (px[0] + px[1] + px[2] + px[3]);
            float mpy = 0.25f * (py[0] + py[1] + py[2] + py[3]);
            float mgx = 0.25f * (gx[0] + gx[1] + gx[2] + gx[3]);
            float mgy = 0.25f * (gy[0] + gy[1] + gy[2] + gy[3]);
            float rel_cons = 0.0f;
#pragma unroll
            for (int i = 0; i < 4; ++i) {
                rel_cons += norm2f((px[i] - mpx) - (gx[i] - mgx),
                                   (py[i] - mpy) - (gy[i] - mgy));
            }
            rel_cons *= 0.25f;

            float L_pos = 0.4f * dist + 0.3f * area_ratio + 0.3f * rel_cons;
            L = 0.4f * L_shape + 0.3f * L_edge + 0.3f * L_pos;
        }
    }

    // ---- reduction: wave64 shuffle -> LDS -> ONE partial store per block ----
#pragma unroll
    for (int off = 32; off > 0; off >>= 1) {
        L     += __shfl_down(L, off, 64);
        vflag += __shfl_down(vflag, off, 64);
    }
    __shared__ float sL[4], sV[4];
    int lane = threadIdx.x & 63;
    int wv   = threadIdx.x >> 6;
    if (lane == 0) { sL[wv] = L; sV[wv] = vflag; }
    __syncthreads();
    if (threadIdx.x == 0) {
        float tL = sL[0] + sL[1] + sL[2] + sL[3];
        float tV = sV[0] + sV[1] + sV[2] + sV[3];
        partials[blockIdx.x] = make_float2(tL, tV);
    }
}

// Stage 2: reduce nPart partials in one block, write final scalar.
__global__ __launch_bounds__(256) void gsc_reduce_kernel(
    const float2* __restrict__ partials, int nPart, float* __restrict__ out)
{
    float sLsum = 0.0f, sVsum = 0.0f;
    for (int i = threadIdx.x; i < nPart; i += 256) {
        float2 p = partials[i];
        sLsum += p.x;
        sVsum += p.y;
    }
#pragma unroll
    for (int off = 32; off > 0; off >>= 1) {
        sLsum += __shfl_down(sLsum, off, 64);
        sVsum += __shfl_down(sVsum, off, 64);
    }
    __shared__ float sL[4], sV[4];
    int lane = threadIdx.x & 63;
    int wv   = threadIdx.x >> 6;
    if (lane == 0) { sL[wv] = sLsum; sV[wv] = sVsum; }
    __syncthreads();
    if (threadIdx.x == 0) {
        float tL = sL[0] + sL[1] + sL[2] + sL[3];
        float tV = sV[0] + sV[1] + sV[2] + sV[3];
        out[0] = (tV > 0.0f) ? (tL / tV) : 0.0f;
    }
}

extern "C" void kernel_launch(void* const* d_in, const int* in_sizes, int n_in,
                              void* d_out, int out_size, void* d_ws, size_t ws_size,
                              hipStream_t stream) {
    const float* pred = (const float*)d_in[0];
    const float* gt   = (const float*)d_in[1];
    float* out = (float*)d_out;
    float2* partials = (float2*)d_ws;   // one float2 per block (16 KB @ 2048 blocks)

    int B = in_sizes[0] / 24;    // 524288

    int block = 256;
    int grid = (B + block - 1) / block;
    gsc_loss_kernel<<<grid, block, 0, stream>>>(pred, gt, partials, B);
    gsc_reduce_kernel<<<1, 256, 0, stream>>>(partials, grid, out);
}

// Round 4
// 124.583 us; speedup vs baseline: 1.3460x; 1.1569x over previous
//
#include <hip/hip_runtime.h>

#define EPS 1e-6f

__device__ __forceinline__ float norm2f(float dx, float dy) {
    return sqrtf(dx * dx + dy * dy);
}

// Select one of 8 SCALAR values by runtime index k (cndmask chain, no
// memory). Array-parameter version defeated SROA -> arrays landed in
// scratch (VGPR_Count=28, WRITE_SIZE=20MB of scratch leakage in R1-R3).
__device__ __forceinline__ float sel8s(int k, float v0, float v1, float v2,
                                       float v3, float v4, float v5, float v6,
                                       float v7) {
    float r = v0;
    r = (k == 1) ? v1 : r;
    r = (k == 2) ? v2 : r;
    r = (k == 3) ? v3 : r;
    r = (k == 4) ? v4 : r;
    r = (k == 5) ? v5 : r;
    r = (k == 6) ? v6 : r;
    r = (k == 7) ? v7 : r;
    return r;
}

__global__ __launch_bounds__(256) void gsc_loss_kernel(
    const float* __restrict__ pred, const float* __restrict__ gt,
    float2* __restrict__ partials, int B)
{
    int b = blockIdx.x * blockDim.x + threadIdx.x;
    float L = 0.0f;
    float vflag = 0.0f;

    if (b < B) {
        const float4* p4 = reinterpret_cast<const float4*>(pred) + (size_t)b * 6;
        const float4* g4 = reinterpret_cast<const float4*>(gt)   + (size_t)b * 6;
        float4 pA = p4[0], pB = p4[1], pC = p4[2], pD = p4[3], pE = p4[4], pF = p4[5];
        float4 gA = g4[0], gB = g4[1], gC = g4[2], gD = g4[3], gE = g4[4], gF = g4[5];

        // unpack 8 keypoints (x,y,z) from 6 float4s — all named scalars
        float px0 = pA.x, py0 = pA.y, pz0 = pA.z;
        float px1 = pA.w, py1 = pB.x, pz1 = pB.y;
        float px2 = pB.z, py2 = pB.w, pz2 = pC.x;
        float px3 = pC.y, py3 = pC.z, pz3 = pC.w;
        float px4 = pD.x, py4 = pD.y, pz4 = pD.z;
        float px5 = pD.w, py5 = pE.x, pz5 = pE.y;
        float px6 = pE.z, py6 = pE.w, pz6 = pF.x;
        float px7 = pF.y, py7 = pF.z, pz7 = pF.w;

        float gx0 = gA.x, gy0 = gA.y, gz0 = gA.z;
        float gx1 = gA.w, gy1 = gB.x, gz1 = gB.y;
        float gx2 = gB.z, gy2 = gB.w, gz2 = gC.x;
        float gx3 = gC.y, gy3 = gC.z, gz3 = gC.w;
        float gx4 = gD.x, gy4 = gD.y, gz4 = gD.z;
        float gx5 = gD.w, gy5 = gE.x, gz5 = gE.y;
        float gx6 = gE.z, gy6 = gE.w, gz6 = gF.x;
        float gx7 = gF.y, gy7 = gF.z, gz7 = gF.w;

        unsigned mask = 0;
        mask |= (pz0 > 0.5f && gz0 > 0.5f) ? 1u   : 0u;
        mask |= (pz1 > 0.5f && gz1 > 0.5f) ? 2u   : 0u;
        mask |= (pz2 > 0.5f && gz2 > 0.5f) ? 4u   : 0u;
        mask |= (pz3 > 0.5f && gz3 > 0.5f) ? 8u   : 0u;
        mask |= (pz4 > 0.5f && gz4 > 0.5f) ? 16u  : 0u;
        mask |= (pz5 > 0.5f && gz5 > 0.5f) ? 32u  : 0u;
        mask |= (pz6 > 0.5f && gz6 > 0.5f) ? 64u  : 0u;
        mask |= (pz7 > 0.5f && gz7 > 0.5f) ? 128u : 0u;

        if (__popc(mask) >= 4) {
            vflag = 1.0f;

            // first 4 visible indices (stable = ascending bit position)
            unsigned m = mask;
            int k0 = __ffs(m) - 1; m &= m - 1;
            int k1 = __ffs(m) - 1; m &= m - 1;
            int k2 = __ffs(m) - 1; m &= m - 1;
            int k3 = __ffs(m) - 1;

            float P1x = sel8s(k0, px0, px1, px2, px3, px4, px5, px6, px7);
            float P1y = sel8s(k0, py0, py1, py2, py3, py4, py5, py6, py7);
            float G1x = sel8s(k0, gx0, gx1, gx2, gx3, gx4, gx5, gx6, gx7);
            float G1y = sel8s(k0, gy0, gy1, gy2, gy3, gy4, gy5, gy6, gy7);
            float P2x = sel8s(k1, px0, px1, px2, px3, px4, px5, px6, px7);
            float P2y = sel8s(k1, py0, py1, py2, py3, py4, py5, py6, py7);
            float G2x = sel8s(k1, gx0, gx1, gx2, gx3, gx4, gx5, gx6, gx7);
            float G2y = sel8s(k1, gy0, gy1, gy2, gy3, gy4, gy5, gy6, gy7);
            float P3x = sel8s(k2, px0, px1, px2, px3, px4, px5, px6, px7);
            float P3y = sel8s(k2, py0, py1, py2, py3, py4, py5, py6, py7);
            float G3x = sel8s(k2, gx0, gx1, gx2, gx3, gx4, gx5, gx6, gx7);
            float G3y = sel8s(k2, gy0, gy1, gy2, gy3, gy4, gy5, gy6, gy7);
            float P4x = sel8s(k3, px0, px1, px2, px3, px4, px5, px6, px7);
            float P4y = sel8s(k3, py0, py1, py2, py3, py4, py5, py6, py7);
            float G4x = sel8s(k3, gx0, gx1, gx2, gx3, gx4, gx5, gx6, gx7);
            float G4y = sel8s(k3, gy0, gy1, gy2, gy3, gy4, gy5, gy6, gy7);

            // ---- L_shape: cross-ratio of diagonals ----
            float pd31x = P3x - P1x, pd31y = P3y - P1y;
            float pd42x = P4x - P2x, pd42y = P4y - P2y;
            float gd31x = G3x - G1x, gd31y = G3y - G1y;
            float gd42x = G4x - G2x, gd42y = G4y - G2y;
            float pred_cr = norm2f(pd31x, pd31y) / (norm2f(pd42x, pd42y) + EPS);
            float gt_cr   = norm2f(gd31x, gd31y) / (norm2f(gd42x, gd42y) + EPS);
            float L_shape = fabsf(pred_cr - gt_cr);

            // ---- L_edge ----
            float v12x = P2x - P1x, v12y = P2y - P1y;
            float v23x = P3x - P2x, v23y = P3y - P2y;
            float v34x = P4x - P3x, v34y = P4y - P3y;
            float v41x = P1x - P4x, v41y = P1y - P4y;
            float l12 = norm2f(v12x, v12y), l23 = norm2f(v23x, v23y);
            float l34 = norm2f(v34x, v34y), l41 = norm2f(v41x, v41y);
            float par1 = fabsf(l12 - l34) / (l12 + l34 + EPS);
            float par2 = fabsf(l23 - l41) / (l23 + l41 + EPS);
            float dot1 = fabsf((v12x * v41x + v12y * v41y) / (l12 * l41 + EPS));
            float dot2 = fabsf((v12x * v23x + v12y * v23y) / (l12 * l23 + EPS));
            float dot3 = fabsf((v23x * v34x + v23y * v34y) / (l23 * l34 + EPS));
            float dot4 = fabsf((v34x * v41x + v34y * v41y) / (l34 * l41 + EPS));
            float L_edge = 0.5f * (par1 + par2) + 0.25f * (dot1 + dot2 + dot3 + dot4);

            // ---- L_pos ----
            float dist = 0.25f * (norm2f(P1x - G1x, P1y - G1y) +
                                  norm2f(P2x - G2x, P2y - G2y) +
                                  norm2f(P3x - G3x, P3y - G3y) +
                                  norm2f(P4x - G4x, P4y - G4y));

            float p21x = P2x - P1x, p21y = P2y - P1y;
            float p41x = P4x - P1x, p41y = P4y - P1y;
            float g21x = G2x - G1x, g21y = G2y - G1y;
            float g41x = G4x - G1x, g41y = G4y - G1y;
            float pred_area = 0.5f * fabsf(p21x * pd31y - p21y * pd31x)
                            + 0.5f * fabsf(pd31x * p41y - pd31y * p41x);
            float gt_area   = 0.5f * fabsf(g21x * gd31y - g21y * gd31x)
                            + 0.5f * fabsf(gd31x * g41y - gd31y * g41x);
            float area_ratio = fabsf(pred_area - gt_area) / (gt_area + EPS);

            float mpx = 0.25f * (P1x + P2x + P3x + P4x);
            float mpy = 0.25f * (P1y + P2y + P3y + P4y);
            float mgx = 0.25f * (G1x + G2x + G3x + G4x);
            float mgy = 0.25f * (G1y + G2y + G3y + G4y);
            float rel_cons = 0.25f *
                (norm2f((P1x - mpx) - (G1x - mgx), (P1y - mpy) - (G1y - mgy)) +
                 norm2f((P2x - mpx) - (G2x - mgx), (P2y - mpy) - (G2y - mgy)) +
                 norm2f((P3x - mpx) - (G3x - mgx), (P3y - mpy) - (G3y - mgy)) +
                 norm2f((P4x - mpx) - (G4x - mgx), (P4y - mpy) - (G4y - mgy)));

            float L_pos = 0.4f * dist + 0.3f * area_ratio + 0.3f * rel_cons;
            L = 0.4f * L_shape + 0.3f * L_edge + 0.3f * L_pos;
        }
    }

    // ---- reduction: wave64 shuffle -> LDS -> ONE partial store per block ----
#pragma unroll
    for (int off = 32; off > 0; off >>= 1) {
        L     += __shfl_down(L, off, 64);
        vflag += __shfl_down(vflag, off, 64);
    }
    __shared__ float sL[4], sV[4];
    int lane = threadIdx.x & 63;
    int wv   = threadIdx.x >> 6;
    if (lane == 0) { sL[wv] = L; sV[wv] = vflag; }
    __syncthreads();
    if (threadIdx.x == 0) {
        float tL = sL[0] + sL[1] + sL[2] + sL[3];
        float tV = sV[0] + sV[1] + sV[2] + sV[3];
        partials[blockIdx.x] = make_float2(tL, tV);
    }
}

// Stage 2: reduce nPart partials in one block, write final scalar.
__global__ __launch_bounds__(256) void gsc_reduce_kernel(
    const float2* __restrict__ partials, int nPart, float* __restrict__ out)
{
    float sLsum = 0.0f, sVsum = 0.0f;
    for (int i = threadIdx.x; i < nPart; i += 256) {
        float2 p = partials[i];
        sLsum += p.x;
        sVsum += p.y;
    }
#pragma unroll
    for (int off = 32; off > 0; off >>= 1) {
        sLsum += __shfl_down(sLsum, off, 64);
        sVsum += __shfl_down(sVsum, off, 64);
    }
    __shared__ float sL[4], sV[4];
    int lane = threadIdx.x & 63;
    int wv   = threadIdx.x >> 6;
    if (lane == 0) { sL[wv] = sLsum; sV[wv] = sVsum; }
    __syncthreads();
    if (threadIdx.x == 0) {
        float tL = sL[0] + sL[1] + sL[2] + sL[3];
        float tV = sV[0] + sV[1] + sV[2] + sV[3];
        out[0] = (tV > 0.0f) ? (tL / tV) : 0.0f;
    }
}

extern "C" void kernel_launch(void* const* d_in, const int* in_sizes, int n_in,
                              void* d_out, int out_size, void* d_ws, size_t ws_size,
                              hipStream_t stream) {
    const float* pred = (const float*)d_in[0];
    const float* gt   = (const float*)d_in[1];
    float* out = (float*)d_out;
    float2* partials = (float2*)d_ws;   // one float2 per block (16 KB @ 2048 blocks)

    int B = in_sizes[0] / 24;    // 524288

    int block = 256;
    int grid = (B + block - 1) / block;
    gsc_loss_kernel<<<grid, block, 0, stream>>>(pred, gt, partials, B);
    gsc_reduce_kernel<<<1, 256, 0, stream>>>(partials, grid, out);
}

// Round 5
// 119.010 us; speedup vs baseline: 1.4090x; 1.0468x over previous
//
#include <hip/hip_runtime.h>

#define EPS 1e-6f
#define NT  256   // threads per block == rows per block (B % 256 == 0)

__device__ __forceinline__ float norm2f(float dx, float dy) {
    return sqrtf(dx * dx + dy * dy);
}

// Scalar-only 8-way select (cndmask chain). Array version defeated SROA ->
// scratch spills (R1-R3: VGPR_Count=28, 20MB scratch WRITE leakage).
__device__ __forceinline__ float sel8s(int k, float v0, float v1, float v2,
                                       float v3, float v4, float v5, float v6,
                                       float v7) {
    float r = v0;
    r = (k == 1) ? v1 : r;
    r = (k == 2) ? v2 : r;
    r = (k == 3) ? v3 : r;
    r = (k == 4) ? v4 : r;
    r = (k == 5) ? v5 : r;
    r = (k == 6) ? v6 : r;
    r = (k == 7) ? v7 : r;
    return r;
}

// Stage one tensor's 256 rows (6 float4 each) into LDS with coalesced global
// loads, rows padded to 7 float4 (112 B): row-read slot 7t+c, gcd(7,8)=1 ->
// conflict-free ds_read_b128 (R2's raw 96B stride was 8-way conflicted).
__device__ __forceinline__ void stage_tensor(const float4* __restrict__ src,
                                             float4* __restrict__ sT, int t) {
#pragma unroll
    for (int i = 0; i < 6; ++i) {
        int f = t + i * NT;          // block-local float4 index 0..1535
        int r = f / 6, c = f - 6 * r;
        sT[r * 7 + c] = src[f];      // lane-consecutive global read
    }
}

__global__ __launch_bounds__(256) void gsc_loss_kernel(
    const float* __restrict__ pred, const float* __restrict__ gt,
    float2* __restrict__ partials, int B)
{
    __shared__ float4 sT[NT * 7];    // 28,672 B -> 5 blocks/CU
    const int t = threadIdx.x;
    const size_t rowBase = (size_t)blockIdx.x * NT;

    // ---- phase 1: pred through LDS -> 24 named scalars ----
    stage_tensor(reinterpret_cast<const float4*>(pred) + rowBase * 6, sT, t);
    __syncthreads();
    float4 pA = sT[t * 7 + 0], pB = sT[t * 7 + 1], pC = sT[t * 7 + 2];
    float4 pD = sT[t * 7 + 3], pE = sT[t * 7 + 4], pF = sT[t * 7 + 5];

    float px0 = pA.x, py0 = pA.y, pz0 = pA.z;
    float px1 = pA.w, py1 = pB.x, pz1 = pB.y;
    float px2 = pB.z, py2 = pB.w, pz2 = pC.x;
    float px3 = pC.y, py3 = pC.z, pz3 = pC.w;
    float px4 = pD.x, py4 = pD.y, pz4 = pD.z;
    float px5 = pD.w, py5 = pE.x, pz5 = pE.y;
    float px6 = pE.z, py6 = pE.w, pz6 = pF.x;
    float px7 = pF.y, py7 = pF.z, pz7 = pF.w;
    __syncthreads();                 // all reads done before overwrite

    // ---- phase 2: gt through the same buffer ----
    stage_tensor(reinterpret_cast<const float4*>(gt) + rowBase * 6, sT, t);
    __syncthreads();
    float4 gA = sT[t * 7 + 0], gB = sT[t * 7 + 1], gC = sT[t * 7 + 2];
    float4 gD = sT[t * 7 + 3], gE = sT[t * 7 + 4], gF = sT[t * 7 + 5];

    float gx0 = gA.x, gy0 = gA.y, gz0 = gA.z;
    float gx1 = gA.w, gy1 = gB.x, gz1 = gB.y;
    float gx2 = gB.z, gy2 = gB.w, gz2 = gC.x;
    float gx3 = gC.y, gy3 = gC.z, gz3 = gC.w;
    float gx4 = gD.x, gy4 = gD.y, gz4 = gD.z;
    float gx5 = gD.w, gy5 = gE.x, gz5 = gE.y;
    float gx6 = gE.z, gy6 = gE.w, gz6 = gF.x;
    float gx7 = gF.y, gy7 = gF.z, gz7 = gF.w;

    float L = 0.0f, vflag = 0.0f;

    unsigned mask = 0;
    mask |= (pz0 > 0.5f && gz0 > 0.5f) ? 1u   : 0u;
    mask |= (pz1 > 0.5f && gz1 > 0.5f) ? 2u   : 0u;
    mask |= (pz2 > 0.5f && gz2 > 0.5f) ? 4u   : 0u;
    mask |= (pz3 > 0.5f && gz3 > 0.5f) ? 8u   : 0u;
    mask |= (pz4 > 0.5f && gz4 > 0.5f) ? 16u  : 0u;
    mask |= (pz5 > 0.5f && gz5 > 0.5f) ? 32u  : 0u;
    mask |= (pz6 > 0.5f && gz6 > 0.5f) ? 64u  : 0u;
    mask |= (pz7 > 0.5f && gz7 > 0.5f) ? 128u : 0u;

    if ((rowBase + t) < (size_t)B && __popc(mask) >= 4) {
        vflag = 1.0f;

        unsigned m = mask;
        int k0 = __ffs(m) - 1; m &= m - 1;
        int k1 = __ffs(m) - 1; m &= m - 1;
        int k2 = __ffs(m) - 1; m &= m - 1;
        int k3 = __ffs(m) - 1;

        float P1x = sel8s(k0, px0, px1, px2, px3, px4, px5, px6, px7);
        float P1y = sel8s(k0, py0, py1, py2, py3, py4, py5, py6, py7);
        float G1x = sel8s(k0, gx0, gx1, gx2, gx3, gx4, gx5, gx6, gx7);
        float G1y = sel8s(k0, gy0, gy1, gy2, gy3, gy4, gy5, gy6, gy7);
        float P2x = sel8s(k1, px0, px1, px2, px3, px4, px5, px6, px7);
        float P2y = sel8s(k1, py0, py1, py2, py3, py4, py5, py6, py7);
        float G2x = sel8s(k1, gx0, gx1, gx2, gx3, gx4, gx5, gx6, gx7);
        float G2y = sel8s(k1, gy0, gy1, gy2, gy3, gy4, gy5, gy6, gy7);
        float P3x = sel8s(k2, px0, px1, px2, px3, px4, px5, px6, px7);
        float P3y = sel8s(k2, py0, py1, py2, py3, py4, py5, py6, py7);
        float G3x = sel8s(k2, gx0, gx1, gx2, gx3, gx4, gx5, gx6, gx7);
        float G3y = sel8s(k2, gy0, gy1, gy2, gy3, gy4, gy5, gy6, gy7);
        float P4x = sel8s(k3, px0, px1, px2, px3, px4, px5, px6, px7);
        float P4y = sel8s(k3, py0, py1, py2, py3, py4, py5, py6, py7);
        float G4x = sel8s(k3, gx0, gx1, gx2, gx3, gx4, gx5, gx6, gx7);
        float G4y = sel8s(k3, gy0, gy1, gy2, gy3, gy4, gy5, gy6, gy7);

        // ---- L_shape ----
        float pd31x = P3x - P1x, pd31y = P3y - P1y;
        float pd42x = P4x - P2x, pd42y = P4y - P2y;
        float gd31x = G3x - G1x, gd31y = G3y - G1y;
        float gd42x = G4x - G2x, gd42y = G4y - G2y;
        float pred_cr = norm2f(pd31x, pd31y) / (norm2f(pd42x, pd42y) + EPS);
        float gt_cr   = norm2f(gd31x, gd31y) / (norm2f(gd42x, gd42y) + EPS);
        float L_shape = fabsf(pred_cr - gt_cr);

        // ---- L_edge ----
        float v12x = P2x - P1x, v12y = P2y - P1y;
        float v23x = P3x - P2x, v23y = P3y - P2y;
        float v34x = P4x - P3x, v34y = P4y - P3y;
        float v41x = P1x - P4x, v41y = P1y - P4y;
        float l12 = norm2f(v12x, v12y), l23 = norm2f(v23x, v23y);
        float l34 = norm2f(v34x, v34y), l41 = norm2f(v41x, v41y);
        float par1 = fabsf(l12 - l34) / (l12 + l34 + EPS);
        float par2 = fabsf(l23 - l41) / (l23 + l41 + EPS);
        float dot1 = fabsf((v12x * v41x + v12y * v41y) / (l12 * l41 + EPS));
        float dot2 = fabsf((v12x * v23x + v12y * v23y) / (l12 * l23 + EPS));
        float dot3 = fabsf((v23x * v34x + v23y * v34y) / (l23 * l34 + EPS));
        float dot4 = fabsf((v34x * v41x + v34y * v41y) / (l34 * l41 + EPS));
        float L_edge = 0.5f * (par1 + par2) + 0.25f * (dot1 + dot2 + dot3 + dot4);

        // ---- L_pos ----
        float dist = 0.25f * (norm2f(P1x - G1x, P1y - G1y) +
                              norm2f(P2x - G2x, P2y - G2y) +
                              norm2f(P3x - G3x, P3y - G3y) +
                              norm2f(P4x - G4x, P4y - G4y));

        float p21x = P2x - P1x, p21y = P2y - P1y;
        float p41x = P4x - P1x, p41y = P4y - P1y;
        float g21x = G2x - G1x, g21y = G2y - G1y;
        float g41x = G4x - G1x, g41y = G4y - G1y;
        float pred_area = 0.5f * fabsf(p21x * pd31y - p21y * pd31x)
                        + 0.5f * fabsf(pd31x * p41y - pd31y * p41x);
        float gt_area   = 0.5f * fabsf(g21x * gd31y - g21y * gd31x)
                        + 0.5f * fabsf(gd31x * g41y - gd31y * g41x);
        float area_ratio = fabsf(pred_area - gt_area) / (gt_area + EPS);

        float mpx = 0.25f * (P1x + P2x + P3x + P4x);
        float mpy = 0.25f * (P1y + P2y + P3y + P4y);
        float mgx = 0.25f * (G1x + G2x + G3x + G4x);
        float mgy = 0.25f * (G1y + G2y + G3y + G4y);
        float rel_cons = 0.25f *
            (norm2f((P1x - mpx) - (G1x - mgx), (P1y - mpy) - (G1y - mgy)) +
             norm2f((P2x - mpx) - (G2x - mgx), (P2y - mpy) - (G2y - mgy)) +
             norm2f((P3x - mpx) - (G3x - mgx), (P3y - mpy) - (G3y - mgy)) +
             norm2f((P4x - mpx) - (G4x - mgx), (P4y - mpy) - (G4y - mgy)));

        float L_pos = 0.4f * dist + 0.3f * area_ratio + 0.3f * rel_cons;
        L = 0.4f * L_shape + 0.3f * L_edge + 0.3f * L_pos;
    }

    // ---- reduction: wave64 shuffle -> LDS -> one partial store per block ----
#pragma unroll
    for (int off = 32; off > 0; off >>= 1) {
        L     += __shfl_down(L, off, 64);
        vflag += __shfl_down(vflag, off, 64);
    }
    __shared__ float sL[4], sV[4];
    int lane = threadIdx.x & 63;
    int wv   = threadIdx.x >> 6;
    if (lane == 0) { sL[wv] = L; sV[wv] = vflag; }
    __syncthreads();
    if (threadIdx.x == 0) {
        float tL = sL[0] + sL[1] + sL[2] + sL[3];
        float tV = sV[0] + sV[1] + sV[2] + sV[3];
        partials[blockIdx.x] = make_float2(tL, tV);
    }
}

// Stage 2: reduce nPart partials in one block, write final scalar.
__global__ __launch_bounds__(256) void gsc_reduce_kernel(
    const float2* __restrict__ partials, int nPart, float* __restrict__ out)
{
    float sLsum = 0.0f, sVsum = 0.0f;
    for (int i = threadIdx.x; i < nPart; i += 256) {
        float2 p = partials[i];
        sLsum += p.x;
        sVsum += p.y;
    }
#pragma unroll
    for (int off = 32; off > 0; off >>= 1) {
        sLsum += __shfl_down(sLsum, off, 64);
        sVsum += __shfl_down(sVsum, off, 64);
    }
    __shared__ float sL[4], sV[4];
    int lane = threadIdx.x & 63;
    int wv   = threadIdx.x >> 6;
    if (lane == 0) { sL[wv] = sLsum; sV[wv] = sVsum; }
    __syncthreads();
    if (threadIdx.x == 0) {
        float tL = sL[0] + sL[1] + sL[2] + sL[3];
        float tV = sV[0] + sV[1] + sV[2] + sV[3];
        out[0] = (tV > 0.0f) ? (tL / tV) : 0.0f;
    }
}

extern "C" void kernel_launch(void* const* d_in, const int* in_sizes, int n_in,
                              void* d_out, int out_size, void* d_ws, size_t ws_size,
                              hipStream_t stream) {
    const float* pred = (const float*)d_in[0];
    const float* gt   = (const float*)d_in[1];
    float* out = (float*)d_out;
    float2* partials = (float2*)d_ws;

    int B = in_sizes[0] / 24;        // 524288 (multiple of 256)
    int grid = (B + NT - 1) / NT;

    gsc_loss_kernel<<<grid, NT, 0, stream>>>(pred, gt, partials, B);
    gsc_reduce_kernel<<<1, 256, 0, stream>>>(partials, grid, out);
}

// Round 6
// 116.839 us; speedup vs baseline: 1.4352x; 1.0186x over previous
//
#include <hip/hip_runtime.h>

#define EPS 1e-6f
#define NT  256   // threads per block == rows per block (B % 256 == 0)

__device__ __forceinline__ float norm2f(float dx, float dy) {
    return sqrtf(dx * dx + dy * dy);
}

// Scalar-only 8-way select (cndmask chain). Array version defeated SROA ->
// scratch spills (R1-R3: VGPR_Count=28, 20MB scratch WRITE leakage).
__device__ __forceinline__ float sel8s(int k, float v0, float v1, float v2,
                                       float v3, float v4, float v5, float v6,
                                       float v7) {
    float r = v0;
    r = (k == 1) ? v1 : r;
    r = (k == 2) ? v2 : r;
    r = (k == 3) ? v3 : r;
    r = (k == 4) ? v4 : r;
    r = (k == 5) ? v5 : r;
    r = (k == 6) ? v6 : r;
    r = (k == 7) ? v7 : r;
    return r;
}

__global__ __launch_bounds__(256) void gsc_loss_kernel(
    const float* __restrict__ pred, const float* __restrict__ gt,
    float2* __restrict__ partials, int B)
{
    // Rows padded to 7 float4 (112 B): row-read slot 7t+c, gcd(7,8)=1 ->
    // conflict-free ds_read_b128. One buffer, two phases (28.7 KB, 5 blk/CU).
    __shared__ float4 sT[NT * 7];
    const int t = threadIdx.x;
    const size_t rowBase = (size_t)blockIdx.x * NT;

    // ---- issue ALL 12 coalesced global loads up front (12 KB/wave in
    // flight; R5's phase-serialized version had only 6 KB and starved HBM) ----
    const float4* p4 = reinterpret_cast<const float4*>(pred) + rowBase * 6;
    const float4* g4 = reinterpret_cast<const float4*>(gt)   + rowBase * 6;
    float4 pr0 = p4[t + 0 * NT], pr1 = p4[t + 1 * NT], pr2 = p4[t + 2 * NT];
    float4 pr3 = p4[t + 3 * NT], pr4 = p4[t + 4 * NT], pr5 = p4[t + 5 * NT];
    float4 gr0 = g4[t + 0 * NT], gr1 = g4[t + 1 * NT], gr2 = g4[t + 2 * NT];
    float4 gr3 = g4[t + 3 * NT], gr4 = g4[t + 4 * NT], gr5 = g4[t + 5 * NT];

    // staging slot for loaded chunk i: f = t + i*NT, slot = 7*(f/6) + f%6
#define SLOT(i) (7 * ((t + (i) * NT) / 6) + ((t + (i) * NT) % 6))
    // ---- phase 1: pred through LDS -> 24 named scalars ----
    sT[SLOT(0)] = pr0; sT[SLOT(1)] = pr1; sT[SLOT(2)] = pr2;
    sT[SLOT(3)] = pr3; sT[SLOT(4)] = pr4; sT[SLOT(5)] = pr5;
    __syncthreads();
    float4 pA = sT[t * 7 + 0], pB = sT[t * 7 + 1], pC = sT[t * 7 + 2];
    float4 pD = sT[t * 7 + 3], pE = sT[t * 7 + 4], pF = sT[t * 7 + 5];

    float px0 = pA.x, py0 = pA.y, pz0 = pA.z;
    float px1 = pA.w, py1 = pB.x, pz1 = pB.y;
    float px2 = pB.z, py2 = pB.w, pz2 = pC.x;
    float px3 = pC.y, py3 = pC.z, pz3 = pC.w;
    float px4 = pD.x, py4 = pD.y, pz4 = pD.z;
    float px5 = pD.w, py5 = pE.x, pz5 = pE.y;
    float px6 = pE.z, py6 = pE.w, pz6 = pF.x;
    float px7 = pF.y, py7 = pF.z, pz7 = pF.w;
    __syncthreads();                 // all phase-1 reads done before overwrite

    // ---- phase 2: gt through the same buffer (data already in registers) ----
    sT[SLOT(0)] = gr0; sT[SLOT(1)] = gr1; sT[SLOT(2)] = gr2;
    sT[SLOT(3)] = gr3; sT[SLOT(4)] = gr4; sT[SLOT(5)] = gr5;
#undef SLOT
    __syncthreads();
    float4 gA = sT[t * 7 + 0], gB = sT[t * 7 + 1], gC = sT[t * 7 + 2];
    float4 gD = sT[t * 7 + 3], gE = sT[t * 7 + 4], gF = sT[t * 7 + 5];

    float gx0 = gA.x, gy0 = gA.y, gz0 = gA.z;
    float gx1 = gA.w, gy1 = gB.x, gz1 = gB.y;
    float gx2 = gB.z, gy2 = gB.w, gz2 = gC.x;
    float gx3 = gC.y, gy3 = gC.z, gz3 = gC.w;
    float gx4 = gD.x, gy4 = gD.y, gz4 = gD.z;
    float gx5 = gD.w, gy5 = gE.x, gz5 = gE.y;
    float gx6 = gE.z, gy6 = gE.w, gz6 = gF.x;
    float gx7 = gF.y, gy7 = gF.z, gz7 = gF.w;

    float L = 0.0f, vflag = 0.0f;

    unsigned mask = 0;
    mask |= (pz0 > 0.5f && gz0 > 0.5f) ? 1u   : 0u;
    mask |= (pz1 > 0.5f && gz1 > 0.5f) ? 2u   : 0u;
    mask |= (pz2 > 0.5f && gz2 > 0.5f) ? 4u   : 0u;
    mask |= (pz3 > 0.5f && gz3 > 0.5f) ? 8u   : 0u;
    mask |= (pz4 > 0.5f && gz4 > 0.5f) ? 16u  : 0u;
    mask |= (pz5 > 0.5f && gz5 > 0.5f) ? 32u  : 0u;
    mask |= (pz6 > 0.5f && gz6 > 0.5f) ? 64u  : 0u;
    mask |= (pz7 > 0.5f && gz7 > 0.5f) ? 128u : 0u;

    if ((rowBase + t) < (size_t)B && __popc(mask) >= 4) {
        vflag = 1.0f;

        unsigned m = mask;
        int k0 = __ffs(m) - 1; m &= m - 1;
        int k1 = __ffs(m) - 1; m &= m - 1;
        int k2 = __ffs(m) - 1; m &= m - 1;
        int k3 = __ffs(m) - 1;

        float P1x = sel8s(k0, px0, px1, px2, px3, px4, px5, px6, px7);
        float P1y = sel8s(k0, py0, py1, py2, py3, py4, py5, py6, py7);
        float G1x = sel8s(k0, gx0, gx1, gx2, gx3, gx4, gx5, gx6, gx7);
        float G1y = sel8s(k0, gy0, gy1, gy2, gy3, gy4, gy5, gy6, gy7);
        float P2x = sel8s(k1, px0, px1, px2, px3, px4, px5, px6, px7);
        float P2y = sel8s(k1, py0, py1, py2, py3, py4, py5, py6, py7);
        float G2x = sel8s(k1, gx0, gx1, gx2, gx3, gx4, gx5, gx6, gx7);
        float G2y = sel8s(k1, gy0, gy1, gy2, gy3, gy4, gy5, gy6, gy7);
        float P3x = sel8s(k2, px0, px1, px2, px3, px4, px5, px6, px7);
        float P3y = sel8s(k2, py0, py1, py2, py3, py4, py5, py6, py7);
        float G3x = sel8s(k2, gx0, gx1, gx2, gx3, gx4, gx5, gx6, gx7);
        float G3y = sel8s(k2, gy0, gy1, gy2, gy3, gy4, gy5, gy6, gy7);
        float P4x = sel8s(k3, px0, px1, px2, px3, px4, px5, px6, px7);
        float P4y = sel8s(k3, py0, py1, py2, py3, py4, py5, py6, py7);
        float G4x = sel8s(k3, gx0, gx1, gx2, gx3, gx4, gx5, gx6, gx7);
        float G4y = sel8s(k3, gy0, gy1, gy2, gy3, gy4, gy5, gy6, gy7);

        // ---- L_shape ----
        float pd31x = P3x - P1x, pd31y = P3y - P1y;
        float pd42x = P4x - P2x, pd42y = P4y - P2y;
        float gd31x = G3x - G1x, gd31y = G3y - G1y;
        float gd42x = G4x - G2x, gd42y = G4y - G2y;
        float pred_cr = norm2f(pd31x, pd31y) / (norm2f(pd42x, pd42y) + EPS);
        float gt_cr   = norm2f(gd31x, gd31y) / (norm2f(gd42x, gd42y) + EPS);
        float L_shape = fabsf(pred_cr - gt_cr);

        // ---- L_edge ----
        float v12x = P2x - P1x, v12y = P2y - P1y;
        float v23x = P3x - P2x, v23y = P3y - P2y;
        float v34x = P4x - P3x, v34y = P4y - P3y;
        float v41x = P1x - P4x, v41y = P1y - P4y;
        float l12 = norm2f(v12x, v12y), l23 = norm2f(v23x, v23y);
        float l34 = norm2f(v34x, v34y), l41 = norm2f(v41x, v41y);
        float par1 = fabsf(l12 - l34) / (l12 + l34 + EPS);
        float par2 = fabsf(l23 - l41) / (l23 + l41 + EPS);
        float dot1 = fabsf((v12x * v41x + v12y * v41y) / (l12 * l41 + EPS));
        float dot2 = fabsf((v12x * v23x + v12y * v23y) / (l12 * l23 + EPS));
        float dot3 = fabsf((v23x * v34x + v23y * v34y) / (l23 * l34 + EPS));
        float dot4 = fabsf((v34x * v41x + v34y * v41y) / (l34 * l41 + EPS));
        float L_edge = 0.5f * (par1 + par2) + 0.25f * (dot1 + dot2 + dot3 + dot4);

        // ---- L_pos ----
        float dist = 0.25f * (norm2f(P1x - G1x, P1y - G1y) +
                              norm2f(P2x - G2x, P2y - G2y) +
                              norm2f(P3x - G3x, P3y - G3y) +
                              norm2f(P4x - G4x, P4y - G4y));

        float p21x = P2x - P1x, p21y = P2y - P1y;
        float p41x = P4x - P1x, p41y = P4y - P1y;
        float g21x = G2x - G1x, g21y = G2y - G1y;
        float g41x = G4x - G1x, g41y = G4y - G1y;
        float pred_area = 0.5f * fabsf(p21x * pd31y - p21y * pd31x)
                        + 0.5f * fabsf(pd31x * p41y - pd31y * p41x);
        float gt_area   = 0.5f * fabsf(g21x * gd31y - g21y * gd31x)
                        + 0.5f * fabsf(gd31x * g41y - gd31y * g41x);
        float area_ratio = fabsf(pred_area - gt_area) / (gt_area + EPS);

        float mpx = 0.25f * (P1x + P2x + P3x + P4x);
        float mpy = 0.25f * (P1y + P2y + P3y + P4y);
        float mgx = 0.25f * (G1x + G2x + G3x + G4x);
        float mgy = 0.25f * (G1y + G2y + G3y + G4y);
        float rel_cons = 0.25f *
            (norm2f((P1x - mpx) - (G1x - mgx), (P1y - mpy) - (G1y - mgy)) +
             norm2f((P2x - mpx) - (G2x - mgx), (P2y - mpy) - (G2y - mgy)) +
             norm2f((P3x - mpx) - (G3x - mgx), (P3y - mpy) - (G3y - mgy)) +
             norm2f((P4x - mpx) - (G4x - mgx), (P4y - mpy) - (G4y - mgy)));

        float L_pos = 0.4f * dist + 0.3f * area_ratio + 0.3f * rel_cons;
        L = 0.4f * L_shape + 0.3f * L_edge + 0.3f * L_pos;
    }

    // ---- reduction: wave64 shuffle -> LDS -> one partial store per block ----
#pragma unroll
    for (int off = 32; off > 0; off >>= 1) {
        L     += __shfl_down(L, off, 64);
        vflag += __shfl_down(vflag, off, 64);
    }
    __shared__ float sL[4], sV[4];
    int lane = threadIdx.x & 63;
    int wv   = threadIdx.x >> 6;
    if (lane == 0) { sL[wv] = L; sV[wv] = vflag; }
    __syncthreads();
    if (threadIdx.x == 0) {
        float tL = sL[0] + sL[1] + sL[2] + sL[3];
        float tV = sV[0] + sV[1] + sV[2] + sV[3];
        partials[blockIdx.x] = make_float2(tL, tV);
    }
}

// Stage 2: reduce nPart partials in one block, write final scalar.
__global__ __launch_bounds__(256) void gsc_reduce_kernel(
    const float2* __restrict__ partials, int nPart, float* __restrict__ out)
{
    float sLsum = 0.0f, sVsum = 0.0f;
    for (int i = threadIdx.x; i < nPart; i += 256) {
        float2 p = partials[i];
        sLsum += p.x;
        sVsum += p.y;
    }
#pragma unroll
    for (int off = 32; off > 0; off >>= 1) {
        sLsum += __shfl_down(sLsum, off, 64);
        sVsum += __shfl_down(sVsum, off, 64);
    }
    __shared__ float sL[4], sV[4];
    int lane = threadIdx.x & 63;
    int wv   = threadIdx.x >> 6;
    if (lane == 0) { sL[wv] = sLsum; sV[wv] = sVsum; }
    __syncthreads();
    if (threadIdx.x == 0) {
        float tL = sL[0] + sL[1] + sL[2] + sL[3];
        float tV = sV[0] + sV[1] + sV[2] + sV[3];
        out[0] = (tV > 0.0f) ? (tL / tV) : 0.0f;
    }
}

extern "C" void kernel_launch(void* const* d_in, const int* in_sizes, int n_in,
                              void* d_out, int out_size, void* d_ws, size_t ws_size,
                              hipStream_t stream) {
    const float* pred = (const float*)d_in[0];
    const float* gt   = (const float*)d_in[1];
    float* out = (float*)d_out;
    float2* partials = (float2*)d_ws;

    int B = in_sizes[0] / 24;        // 524288 (multiple of 256)
    int grid = (B + NT - 1) / NT;

    gsc_loss_kernel<<<grid, NT, 0, stream>>>(pred, gt, partials, B);
    gsc_reduce_kernel<<<1, 256, 0, stream>>>(partials, grid, out);
}